// Round 1
// baseline (291.984 us; speedup 1.0000x reference)
//
#include <hip/hip_runtime.h>
#include <math.h>

#define PROJ 8192
#define NB   16
#define NC   512
#define HW   196    // 14*14

#define TILE  64
#define KCH   96
#define LDSTR 100   // 96 + 4 pad: float4-aligned rows, breaks bank aliasing

// ---------------------------------------------------------------------------
// Kernel 0: zero the accumulator (d_out is poisoned 0xAA before every call)
// ---------------------------------------------------------------------------
__global__ void cbp_zero(float* __restrict__ y) {
    int i = blockIdx.x * blockDim.x + threadIdx.x;
    if (i < NB * PROJ) y[i] = 0.0f;
}

// ---------------------------------------------------------------------------
// Kernel 1: fused Gram + count-sketch scatter.
//   block = 256 threads -> 64x64 tile of G[b], thread computes 4x4 entries
//   grid  = 16 * 8 * 8 = 1024 blocks
//   epilogue: atomicAdd(y[b][(h1[c1]+h2[c2]) & 8191], s1[c1]*s2[c2]*G)
// ---------------------------------------------------------------------------
__global__ __launch_bounds__(256)
void cbp_gram_scatter(const float* __restrict__ x,
                      const float* __restrict__ s1,
                      const float* __restrict__ s2,
                      const int*   __restrict__ h1,
                      const int*   __restrict__ h2,
                      float* __restrict__ y) {
    __shared__ float As[TILE * LDSTR];
    __shared__ float Bs[TILE * LDSTR];

    const int blk = blockIdx.x;
    const int b  = blk >> 6;
    const int I  = (blk >> 3) & 7;
    const int J  = blk & 7;
    const int c1base = I * TILE;
    const int c2base = J * TILE;

    const int tid = threadIdx.x;
    const int tx = tid & 15;   // column group (c2 = c2base + tx + 16j)
    const int ty = tid >> 4;   // row group    (c1 = c1base + ty + 16i)

    const float* xa = x + ((size_t)b * NC + c1base) * HW;
    const float* xb = x + ((size_t)b * NC + c2base) * HW;

    float acc[4][4] = {{0.f}};

    for (int k0 = 0; k0 < HW; k0 += KCH) {
        const int kc = min(KCH, HW - k0);   // 96, 96, 4 (all multiples of 4)

        // Stage 64 x kc tiles. Consecutive tids -> consecutive k within a row:
        // coalesced global reads, conflict-free LDS writes.
        for (int e = tid; e < TILE * KCH; e += 256) {
            const int r = e / KCH;          // constant divisor -> magic mul
            const int k = e - r * KCH;
            if (k < kc) {
                As[r * LDSTR + k] = xa[r * HW + k0 + k];
                Bs[r * LDSTR + k] = xb[r * HW + k0 + k];
            }
        }
        __syncthreads();

        for (int k = 0; k < kc; k += 4) {
            float4 av[4], bv[4];
#pragma unroll
            for (int i = 0; i < 4; i++)
                av[i] = *(const float4*)&As[(ty + 16 * i) * LDSTR + k];
#pragma unroll
            for (int j = 0; j < 4; j++)
                bv[j] = *(const float4*)&Bs[(tx + 16 * j) * LDSTR + k];
#pragma unroll
            for (int i = 0; i < 4; i++)
#pragma unroll
                for (int j = 0; j < 4; j++) {
                    acc[i][j] += av[i].x * bv[j].x;
                    acc[i][j] += av[i].y * bv[j].y;
                    acc[i][j] += av[i].z * bv[j].z;
                    acc[i][j] += av[i].w * bv[j].w;
                }
        }
        __syncthreads();
    }

    // Epilogue: sign-weight + scatter into the 8192-bin sketch for batch b.
    int   ha[4], hb[4];
    float sa[4], sb[4];
#pragma unroll
    for (int i = 0; i < 4; i++) {
        const int c1 = c1base + ty + 16 * i;
        ha[i] = h1[c1];
        sa[i] = s1[c1];
    }
#pragma unroll
    for (int j = 0; j < 4; j++) {
        const int c2 = c2base + tx + 16 * j;
        hb[j] = h2[c2];
        sb[j] = s2[c2];
    }

    float* yb = y + (size_t)b * PROJ;
#pragma unroll
    for (int i = 0; i < 4; i++)
#pragma unroll
        for (int j = 0; j < 4; j++) {
            const int bin = (ha[i] + hb[j]) & (PROJ - 1);
            atomicAdd(&yb[bin], sa[i] * sb[j] * acc[i][j]);
        }
}

// ---------------------------------------------------------------------------
// Kernel 2: in-place signed sqrt + per-row L2 normalize. One block per batch.
// ---------------------------------------------------------------------------
__global__ __launch_bounds__(256)
void cbp_normalize(float* __restrict__ y) {
    const int b   = blockIdx.x;
    const int tid = threadIdx.x;
    float* row = y + (size_t)b * PROJ;

    float v[PROJ / 256];
    float ssq = 0.f;
#pragma unroll
    for (int j = 0; j < PROJ / 256; j++) {
        const float t = row[j * 256 + tid];
        const float m = sqrtf(fabsf(t) + 1e-8f);
        const float vv = (t > 0.f) ? m : (t < 0.f ? -m : 0.f); // sign(0)=0
        v[j] = vv;
        ssq += vv * vv;
    }

    __shared__ float red[256];
    red[tid] = ssq;
    __syncthreads();
#pragma unroll
    for (int s = 128; s >= 1; s >>= 1) {
        if (tid < s) red[tid] += red[tid + s];
        __syncthreads();
    }
    const float norm = sqrtf(red[0]);
    const float inv  = 1.0f / fmaxf(norm, 1e-12f);

#pragma unroll
    for (int j = 0; j < PROJ / 256; j++)
        row[j * 256 + tid] = v[j] * inv;
}

// ---------------------------------------------------------------------------
extern "C" void kernel_launch(void* const* d_in, const int* in_sizes, int n_in,
                              void* d_out, int out_size, void* d_ws, size_t ws_size,
                              hipStream_t stream) {
    const float* x  = (const float*)d_in[0];
    const float* s1 = (const float*)d_in[1];
    const float* s2 = (const float*)d_in[2];
    const int*   h1 = (const int*)d_in[3];
    const int*   h2 = (const int*)d_in[4];
    float* y = (float*)d_out;   // [16, 8192]

    hipLaunchKernelGGL(cbp_zero, dim3((NB * PROJ) / 256), dim3(256), 0, stream, y);
    hipLaunchKernelGGL(cbp_gram_scatter, dim3(NB * 8 * 8), dim3(256), 0, stream,
                       x, s1, s2, h1, h2, y);
    hipLaunchKernelGGL(cbp_normalize, dim3(NB), dim3(256), 0, stream, y);
}

// Round 2
// 128.413 us; speedup vs baseline: 2.2738x; 2.2738x over previous
//
#include <hip/hip_runtime.h>
#include <math.h>

#define PROJ 8192
#define NB   16
#define NC   512
#define HW   196    // 14*14

#define TB   128    // Gram tile (128x128 per block)
#define KCH  20     // K chunk (196 = 9*20 + 16; both chunk sizes are x4)
#define LSA  24     // As row stride (floats): rows 0..3 -> banks 0,24,16,8 (distinct)
#define LSB  36     // Bs row stride (floats): 36 % 32 == 4 -> 16 rows = 2-way (free)

// ---------------------------------------------------------------------------
// Kernel 0: zero the 16 per-batch sum-of-squares accumulators in ws tail.
// ---------------------------------------------------------------------------
__global__ void cbp_zero_ssq(float* __restrict__ ssq) {
    if (threadIdx.x < NB) ssq[threadIdx.x] = 0.0f;
}

// ---------------------------------------------------------------------------
// Kernel 1: Gram tile + count-sketch scatter into a PRIVATE LDS sketch,
// then dense coalesced write of the partial sketch to workspace.
//   grid = 16 batches * 4x4 tiles = 256 blocks (1 per CU)
//   block = 256 threads, 8x8 accumulators each
// ---------------------------------------------------------------------------
__global__ __launch_bounds__(256)
void cbp_gram_scatter(const float* __restrict__ x,
                      const float* __restrict__ s1,
                      const float* __restrict__ s2,
                      const int*   __restrict__ h1,
                      const int*   __restrict__ h2,
                      float* __restrict__ ws) {
    __shared__ float sk[PROJ];        // 32 KB private sketch
    __shared__ float As[TB * LSA];    // 12 KB
    __shared__ float Bs[TB * LSB];    // 18 KB   -> 62 KB total

    const int blk = blockIdx.x;
    const int b = blk >> 4;
    const int I = (blk >> 2) & 3;
    const int J = blk & 3;
    const int c1base = I * TB;
    const int c2base = J * TB;

    const int tid = threadIdx.x;
    const int tx = tid & 15;     // col group: c2 = c2base + tx + 16j
    const int ty = tid >> 4;     // row group: c1 = c1base + ty + 16i

    // zero the private sketch
    for (int i = tid; i < PROJ; i += 256) sk[i] = 0.0f;

    const float* xa = x + ((size_t)b * NC + c1base) * HW;
    const float* xb = x + ((size_t)b * NC + c2base) * HW;

    float acc[8][8] = {{0.f}};

    for (int k0 = 0; k0 < HW; k0 += KCH) {
        const int kc = (k0 + KCH <= HW) ? KCH : (HW - k0);   // 20 ... 20, 16
        const int kq = kc >> 2;                              // float4 groups: 5 or 4

        __syncthreads();
        // Stage A and B chunks as float4 (rows 16B-aligned: HW%4==0, k0%4==0).
        for (int e = tid; e < TB * (KCH / 4); e += 256) {
            const int r = e / (KCH / 4);          // /5 -> magic mul
            const int q = e - r * (KCH / 4);
            if (q < kq) {
                const float4 a4 = *(const float4*)&xa[r * HW + k0 + 4 * q];
                const float4 b4 = *(const float4*)&xb[r * HW + k0 + 4 * q];
                *(float4*)&As[r * LSA + 4 * q] = a4;
                *(float4*)&Bs[r * LSB + 4 * q] = b4;
            }
        }
        __syncthreads();

        for (int k = 0; k < kc; k += 4) {
            float4 av[8], bv[8];
#pragma unroll
            for (int i = 0; i < 8; i++)
                av[i] = *(const float4*)&As[(ty + 16 * i) * LSA + k];
#pragma unroll
            for (int j = 0; j < 8; j++)
                bv[j] = *(const float4*)&Bs[(tx + 16 * j) * LSB + k];
#pragma unroll
            for (int i = 0; i < 8; i++)
#pragma unroll
                for (int j = 0; j < 8; j++) {
                    acc[i][j] += av[i].x * bv[j].x;
                    acc[i][j] += av[i].y * bv[j].y;
                    acc[i][j] += av[i].z * bv[j].z;
                    acc[i][j] += av[i].w * bv[j].w;
                }
        }
    }
    __syncthreads();

    // Scatter the 8x8 accumulators into the private LDS sketch.
    int   ha[8], hb[8];
    float sa[8], sb[8];
#pragma unroll
    for (int i = 0; i < 8; i++) {
        const int c1 = c1base + ty + 16 * i;
        ha[i] = h1[c1];  sa[i] = s1[c1];
    }
#pragma unroll
    for (int j = 0; j < 8; j++) {
        const int c2 = c2base + tx + 16 * j;
        hb[j] = h2[c2];  sb[j] = s2[c2];
    }
#pragma unroll
    for (int i = 0; i < 8; i++)
#pragma unroll
        for (int j = 0; j < 8; j++) {
            const int bin = (ha[i] + hb[j]) & (PROJ - 1);
            atomicAdd(&sk[bin], sa[i] * sb[j] * acc[i][j]);   // ds_add_f32
        }
    __syncthreads();

    // Dense coalesced dump of the partial sketch.
    float4* dst = (float4*)(ws + (size_t)blk * PROJ);
    const float4* src = (const float4*)sk;
    for (int i = tid; i < PROJ / 4; i += 256) dst[i] = src[i];
}

// ---------------------------------------------------------------------------
// Kernel 2: reduce 16 partial sketches per batch + signed sqrt; accumulate
// per-batch sum-of-squares. grid = 16*8 = 128 blocks, 1024 bins each.
// ---------------------------------------------------------------------------
__global__ __launch_bounds__(256)
void cbp_reduce(const float* __restrict__ ws, float* __restrict__ y,
                float* __restrict__ ssq) {
    const int b   = blockIdx.x >> 3;
    const int seg = blockIdx.x & 7;
    const int tid = threadIdx.x;
    const int bin = seg * 1024 + tid * 4;

    float4 s = {0.f, 0.f, 0.f, 0.f};
#pragma unroll
    for (int t = 0; t < 16; t++) {
        const float4 v = *(const float4*)&ws[((size_t)(b * 16 + t)) * PROJ + bin];
        s.x += v.x; s.y += v.y; s.z += v.z; s.w += v.w;
    }

    float4 o;
    float ls = 0.f;
    {
        float m;
        m = sqrtf(fabsf(s.x) + 1e-8f); o.x = (s.x > 0.f) ? m : (s.x < 0.f ? -m : 0.f);
        m = sqrtf(fabsf(s.y) + 1e-8f); o.y = (s.y > 0.f) ? m : (s.y < 0.f ? -m : 0.f);
        m = sqrtf(fabsf(s.z) + 1e-8f); o.z = (s.z > 0.f) ? m : (s.z < 0.f ? -m : 0.f);
        m = sqrtf(fabsf(s.w) + 1e-8f); o.w = (s.w > 0.f) ? m : (s.w < 0.f ? -m : 0.f);
        ls = o.x * o.x + o.y * o.y + o.z * o.z + o.w * o.w;
    }
    *(float4*)&y[(size_t)b * PROJ + bin] = o;

    __shared__ float red[256];
    red[tid] = ls;
    __syncthreads();
#pragma unroll
    for (int st = 128; st >= 1; st >>= 1) {
        if (tid < st) red[tid] += red[tid + st];
        __syncthreads();
    }
    if (tid == 0) atomicAdd(&ssq[b], red[0]);
}

// ---------------------------------------------------------------------------
// Kernel 3: scale each batch row by 1/max(||y||, 1e-12). grid = 32 blocks.
// ---------------------------------------------------------------------------
__global__ __launch_bounds__(256)
void cbp_normalize(float* __restrict__ y, const float* __restrict__ ssq) {
    const int b   = blockIdx.x >> 1;
    const int off = (blockIdx.x & 1) * 4096;
    const int tid = threadIdx.x;
    const float inv = 1.0f / fmaxf(sqrtf(ssq[b]), 1e-12f);

    float4* row = (float4*)&y[(size_t)b * PROJ + off];
#pragma unroll
    for (int j = 0; j < 4; j++) {
        float4 v = row[j * 256 + tid];
        v.x *= inv; v.y *= inv; v.z *= inv; v.w *= inv;
        row[j * 256 + tid] = v;
    }
}

// ---------------------------------------------------------------------------
extern "C" void kernel_launch(void* const* d_in, const int* in_sizes, int n_in,
                              void* d_out, int out_size, void* d_ws, size_t ws_size,
                              hipStream_t stream) {
    const float* x  = (const float*)d_in[0];
    const float* s1 = (const float*)d_in[1];
    const float* s2 = (const float*)d_in[2];
    const int*   h1 = (const int*)d_in[3];
    const int*   h2 = (const int*)d_in[4];
    float* y  = (float*)d_out;                     // [16, 8192]
    float* ws = (float*)d_ws;                      // 256 partial sketches
    float* ssq = ws + (size_t)256 * PROJ;          // +16 floats

    hipLaunchKernelGGL(cbp_zero_ssq, dim3(1), dim3(64), 0, stream, ssq);
    hipLaunchKernelGGL(cbp_gram_scatter, dim3(NB * 16), dim3(256), 0, stream,
                       x, s1, s2, h1, h2, ws);
    hipLaunchKernelGGL(cbp_reduce, dim3(NB * 8), dim3(256), 0, stream, ws, y, ssq);
    hipLaunchKernelGGL(cbp_normalize, dim3(32), dim3(256), 0, stream, y, ssq);
}

// Round 4
// 111.177 us; speedup vs baseline: 2.6263x; 1.1550x over previous
//
#include <hip/hip_runtime.h>
#include <math.h>

#define PROJ 8192
#define NB   16
#define NC   512
#define HW   196    // 14*14
#define NKC  7      // K chunks of 32 (196 zero-padded to 224)
#define LST  40     // LDS row stride in bf16 elems (80 B: 16B-aligned, ~2-way banks)

typedef __attribute__((ext_vector_type(8))) short bf16x8;   // MFMA A/B frag
typedef __attribute__((ext_vector_type(4))) short short4v;
typedef __attribute__((ext_vector_type(4))) float f32x4;    // MFMA C/D frag

__device__ __forceinline__ unsigned bf16_rne(float f) {
    // round-to-nearest-even fp32 -> bf16 bits (inputs are finite normals)
    unsigned u = __builtin_bit_cast(unsigned, f);
    return (u + 0x7fffu + ((u >> 16) & 1u)) >> 16;
}

// ---------------------------------------------------------------------------
// Kernel 1: split-bf16 MFMA Gram (128x128 tile) + sign-weighted scatter into
// a private 32KB LDS sketch, dense dump to ws.  grid = 16 batches x 16 tiles.
//   G = hi*hi^T + hi*lo^T + lo*hi^T  (lo*lo dropped: rel err ~2^-18)
// ---------------------------------------------------------------------------
__global__ __launch_bounds__(256)
void cbp_gram_mfma(const float* __restrict__ x,
                   const float* __restrict__ s1,
                   const float* __restrict__ s2,
                   const int*   __restrict__ h1,
                   const int*   __restrict__ h2,
                   float* __restrict__ ws) {
    __shared__ float sk[PROJ];         // 32 KB private sketch
    __shared__ short Ah[128 * LST];    // 10 KB each: hi/lo bf16 stages
    __shared__ short Al[128 * LST];
    __shared__ short Bh[128 * LST];
    __shared__ short Bl[128 * LST];
    __shared__ int   lh1[128], lh2[128];
    __shared__ float ls1[128], ls2[128];

    const int tid  = threadIdx.x;
    const int blk  = blockIdx.x;
    const int b    = blk >> 4;
    const int I    = (blk >> 2) & 3;
    const int J    = blk & 3;
    const int c1base = I * 128;
    const int c2base = J * 128;

    const int lane = tid & 63;
    const int wave = tid >> 6;
    const int quad = lane >> 4;
    const int l15  = lane & 15;
    const int wr   = (wave >> 1) * 64;   // wave's row corner in the 128x128 tile
    const int wc   = (wave & 1) * 64;    // wave's col corner

    for (int i = tid; i < PROJ; i += 256) sk[i] = 0.f;
    if (tid < 128) {
        lh1[tid] = h1[c1base + tid]; ls1[tid] = s1[c1base + tid];
        lh2[tid] = h2[c2base + tid]; ls2[tid] = s2[c2base + tid];
    }

    const float* xa = x + ((size_t)b * NC + c1base) * HW;
    const float* xb = x + ((size_t)b * NC + c2base) * HW;

    f32x4 acc[4][4];
#pragma unroll
    for (int i = 0; i < 4; ++i)
#pragma unroll
        for (int j = 0; j < 4; ++j)
            acc[i][j] = (f32x4){0.f, 0.f, 0.f, 0.f};

    for (int kc = 0; kc < NKC; ++kc) {
        const int k0 = kc * 32;
        __syncthreads();
        // Stage 128 rows x 32 k as split bf16; 1024 float4 slots/side.
#pragma unroll
        for (int it = 0; it < 4; ++it) {
            const int s  = tid + 256 * it;
            const int r  = s >> 3;
            const int q  = s & 7;
            const int kk = k0 + 4 * q;
            float4 va = {0.f, 0.f, 0.f, 0.f}, vb = {0.f, 0.f, 0.f, 0.f};
            if (kk + 3 < HW) {   // zero-pad K 196->224
                va = *(const float4*)&xa[r * HW + kk];
                vb = *(const float4*)&xb[r * HW + kk];
            }
            short4v ah, al, bh, bl;
            const float fa[4] = {va.x, va.y, va.z, va.w};
            const float fb[4] = {vb.x, vb.y, vb.z, vb.w};
#pragma unroll
            for (int c = 0; c < 4; ++c) {
                const unsigned ha_ = bf16_rne(fa[c]);
                ah[c] = (short)ha_;
                al[c] = (short)bf16_rne(fa[c] - __builtin_bit_cast(float, ha_ << 16));
                const unsigned hb_ = bf16_rne(fb[c]);
                bh[c] = (short)hb_;
                bl[c] = (short)bf16_rne(fb[c] - __builtin_bit_cast(float, hb_ << 16));
            }
            *(short4v*)&Ah[r * LST + 4 * q] = ah;
            *(short4v*)&Al[r * LST + 4 * q] = al;
            *(short4v*)&Bh[r * LST + 4 * q] = bh;
            *(short4v*)&Bl[r * LST + 4 * q] = bl;
        }
        __syncthreads();

        // Fragment loads: A[m=lane&15][k=quad*8+j] pattern (gemm_bt layout).
        bf16x8 ahf[4], alf[4], bhf[4], blf[4];
#pragma unroll
        for (int i = 0; i < 4; ++i) {
            const int ra = wr + i * 16 + l15;
            const int rb = wc + i * 16 + l15;
            ahf[i] = *(const bf16x8*)&Ah[ra * LST + quad * 8];
            alf[i] = *(const bf16x8*)&Al[ra * LST + quad * 8];
            bhf[i] = *(const bf16x8*)&Bh[rb * LST + quad * 8];
            blf[i] = *(const bf16x8*)&Bl[rb * LST + quad * 8];
        }
#pragma unroll
        for (int i = 0; i < 4; ++i)
#pragma unroll
            for (int j = 0; j < 4; ++j) {
                acc[i][j] = __builtin_amdgcn_mfma_f32_16x16x32_bf16(ahf[i], bhf[j], acc[i][j], 0, 0, 0);
                acc[i][j] = __builtin_amdgcn_mfma_f32_16x16x32_bf16(ahf[i], blf[j], acc[i][j], 0, 0, 0);
                acc[i][j] = __builtin_amdgcn_mfma_f32_16x16x32_bf16(alf[i], bhf[j], acc[i][j], 0, 0, 0);
            }
    }
    __syncthreads();

    // Scatter: C/D layout col=lane&15, row=quad*4+reg (m89-verified).
#pragma unroll
    for (int i = 0; i < 4; ++i) {
        const int lr0 = wr + i * 16 + quad * 4;
#pragma unroll
        for (int j = 0; j < 4; ++j) {
            const int lc   = wc + j * 16 + l15;
            const int h2v  = lh2[lc];
            const float s2v = ls2[lc];
#pragma unroll
            for (int rg = 0; rg < 4; ++rg) {
                const int lr  = lr0 + rg;
                const int bin = (lh1[lr] + h2v) & (PROJ - 1);
                atomicAdd(&sk[bin], ls1[lr] * s2v * acc[i][j][rg]);  // ds_add_f32
            }
        }
    }
    __syncthreads();

    float4* dst = (float4*)(ws + (size_t)blk * PROJ);
    const float4* src = (const float4*)sk;
    for (int i = tid; i < PROJ / 4; i += 256) dst[i] = src[i];
}

// ---------------------------------------------------------------------------
// Kernel 2: sum 16 partial sketches/bin + signed sqrt + per-block ssq partial.
// grid = 16 batches x 32 segs = 512 blocks; fully coalesced.
// ---------------------------------------------------------------------------
__global__ __launch_bounds__(256)
void cbp_reduce(const float* __restrict__ ws, float* __restrict__ y,
                float* __restrict__ ssqp) {
    const int blk = blockIdx.x;
    const int b   = blk >> 5;
    const int seg = blk & 31;
    const int tid = threadIdx.x;
    const int bin = seg * 256 + tid;

    const float* base = ws + (size_t)b * 16 * PROJ + bin;
    float s = 0.f;
#pragma unroll
    for (int p = 0; p < 16; ++p) s += base[(size_t)p * PROJ];

    const float m = sqrtf(fabsf(s) + 1e-8f);
    const float o = (s > 0.f) ? m : (s < 0.f ? -m : 0.f);   // sign(0)=0
    y[b * PROJ + bin] = o;

    __shared__ float red[256];
    red[tid] = o * o;
    __syncthreads();
#pragma unroll
    for (int st = 128; st >= 1; st >>= 1) {
        if (tid < st) red[tid] += red[tid + st];
        __syncthreads();
    }
    if (tid == 0) ssqp[blk] = red[0];
}

// ---------------------------------------------------------------------------
// Kernel 3: scale each batch row by 1/max(||y_b||, 1e-12). grid = 32.
// ---------------------------------------------------------------------------
__global__ __launch_bounds__(256)
void cbp_normalize(float* __restrict__ y, const float* __restrict__ ssqp) {
    const int b   = blockIdx.x >> 1;
    const int off = (blockIdx.x & 1) * 4096;
    const int tid = threadIdx.x;
    float ssq = 0.f;
#pragma unroll
    for (int i = 0; i < 32; ++i) ssq += ssqp[b * 32 + i];
    const float inv = 1.0f / fmaxf(sqrtf(ssq), 1e-12f);

    float4* row = (float4*)&y[(size_t)b * PROJ + off];
#pragma unroll
    for (int j = 0; j < 4; ++j) {
        float4 v = row[j * 256 + tid];
        v.x *= inv; v.y *= inv; v.z *= inv; v.w *= inv;
        row[j * 256 + tid] = v;
    }
}

// ---------------------------------------------------------------------------
extern "C" void kernel_launch(void* const* d_in, const int* in_sizes, int n_in,
                              void* d_out, int out_size, void* d_ws, size_t ws_size,
                              hipStream_t stream) {
    const float* x  = (const float*)d_in[0];
    const float* s1 = (const float*)d_in[1];
    const float* s2 = (const float*)d_in[2];
    const int*   h1 = (const int*)d_in[3];
    const int*   h2 = (const int*)d_in[4];
    float* y    = (float*)d_out;                   // [16, 8192]
    float* ws   = (float*)d_ws;                    // 256 partial sketches (8 MB)
    float* ssqp = ws + (size_t)256 * PROJ;         // + 512 floats

    hipLaunchKernelGGL(cbp_gram_mfma, dim3(NB * 16), dim3(256), 0, stream,
                       x, s1, s2, h1, h2, ws);
    hipLaunchKernelGGL(cbp_reduce, dim3(512), dim3(256), 0, stream, ws, y, ssqp);
    hipLaunchKernelGGL(cbp_normalize, dim3(32), dim3(256), 0, stream, y, ssqp);
}